// Round 1
// baseline (254.561 us; speedup 1.0000x reference)
//
#include <hip/hip_runtime.h>

// Problem constants (from reference):
//   img: [B=256, C=3, H=224, W=224] float32
//   y_idx, x_idx: [B] int32, square size 32
// Zero a 32x32 square per batch (all channels), copy everything else.
// Memory-bound: ~308 MB traffic -> ~49 us floor at 6.3 TB/s.

#define SQ 32
#define B_ 256
#define C_ 3
#define H_ 224
#define W_ 224

__global__ __launch_bounds__(256) void rsd_kernel(const float4* __restrict__ img,
                                                  const int* __restrict__ y_idx,
                                                  const int* __restrict__ x_idx,
                                                  float4* __restrict__ out,
                                                  int total4) {
    int i4 = blockIdx.x * 256 + threadIdx.x;
    if (i4 >= total4) return;

    float4 v = img[i4];

    int i = i4 << 2;                 // flat element index of lane 0 of this float4
    int w = i % W_;                  // column of first element
    int t = i / W_;                  // row index within [B*C*H]
    int h = t % H_;
    int b = t / (C_ * H_);

    int y0 = y_idx[b];
    int x0 = x_idx[b];

    bool row_in = (h >= y0) & (h < y0 + SQ);
    if (row_in) {
        // zero lanes whose column falls in [x0, x0+SQ)
        if ((w + 0) >= x0 && (w + 0) < x0 + SQ) v.x = 0.0f;
        if ((w + 1) >= x0 && (w + 1) < x0 + SQ) v.y = 0.0f;
        if ((w + 2) >= x0 && (w + 2) < x0 + SQ) v.z = 0.0f;
        if ((w + 3) >= x0 && (w + 3) < x0 + SQ) v.w = 0.0f;
    }

    out[i4] = v;
}

extern "C" void kernel_launch(void* const* d_in, const int* in_sizes, int n_in,
                              void* d_out, int out_size, void* d_ws, size_t ws_size,
                              hipStream_t stream) {
    const float4* img  = (const float4*)d_in[0];
    const int*    yidx = (const int*)d_in[1];
    const int*    xidx = (const int*)d_in[2];
    float4*       out  = (float4*)d_out;

    int total4 = out_size / 4;       // 38,535,168 / 4 = 9,633,792
    int blocks = (total4 + 255) / 256;
    rsd_kernel<<<blocks, 256, 0, stream>>>(img, yidx, xidx, out, total4);
}